// Round 1
// baseline (644.449 us; speedup 1.0000x reference)
//
#include <hip/hip_runtime.h>
#include <hip/hip_bf16.h>

// SAGE 2-layer forward:
//   neigh1 = segment_mean(x[src] by dst); h = relu(x@Ws1 + neigh1@Wn1 + b1)
//   neigh2 = segment_mean(h[src] by dst); out = log_softmax(h@Ws2 + neigh2@Wn2 + b2)
// Strategy: build CSR (deg -> scan -> scatter) then atomic-free per-node gather.
// x/h are 51.2MB each -> gathers served by Infinity Cache.
// GEMM1 is fp32 vector (no fp32 MFMA on CDNA4): 64x128 tile, 8x4 reg blocking.

#define N_FEAT 128

__global__ void deg_kernel(const int* __restrict__ dst, int* __restrict__ deg, int E) {
    int e = blockIdx.x * 256 + threadIdx.x;
    if (e < E) atomicAdd(&deg[dst[e]], 1);
}

__global__ void scan_block(const int* __restrict__ deg, int* __restrict__ excl,
                           int* __restrict__ bsum, int n) {
    __shared__ int s[256];
    int tid = threadIdx.x;
    int i = blockIdx.x * 256 + tid;
    int v = (i < n) ? deg[i] : 0;
    int val = v;
    s[tid] = val;
    __syncthreads();
    for (int off = 1; off < 256; off <<= 1) {
        int t = (tid >= off) ? s[tid - off] : 0;
        __syncthreads();
        val += t;
        s[tid] = val;
        __syncthreads();
    }
    if (i < n) excl[i] = val - v;           // exclusive prefix within block
    if (tid == 255) bsum[blockIdx.x] = val; // block total
}

__global__ void scan_sums(int* __restrict__ bsum, int nb) {
    if (threadIdx.x == 0 && blockIdx.x == 0) {
        int acc = 0;
        for (int i = 0; i < nb; ++i) { int t = bsum[i]; bsum[i] = acc; acc += t; }
    }
}

__global__ void scan_add(const int* __restrict__ excl, const int* __restrict__ bsum,
                         int* __restrict__ row_ptr, int n, int E) {
    int i = blockIdx.x * 256 + threadIdx.x;
    if (i < n) row_ptr[i] = excl[i] + bsum[blockIdx.x];
    if (i == 0) row_ptr[n] = E;
}

__global__ void scatter_kernel(const int* __restrict__ src, const int* __restrict__ dst,
                               const int* __restrict__ row_ptr, int* __restrict__ cnt,
                               int* __restrict__ csr, int E) {
    int e = blockIdx.x * 256 + threadIdx.x;
    if (e < E) {
        int d = dst[e];
        int pos = row_ptr[d] + atomicAdd(&cnt[d], 1);
        csr[pos] = src[e];
    }
}

// One wave (64 lanes) per node; lane handles 2 features as float2 (512B/row coalesced).
__global__ void aggregate_kernel(const float* __restrict__ feat,
                                 const int* __restrict__ row_ptr,
                                 const int* __restrict__ csr,
                                 float* __restrict__ out, int n) {
    int v = blockIdx.x * 4 + (threadIdx.x >> 6);
    int lane = threadIdx.x & 63;
    if (v >= n) return;
    int beg = row_ptr[v];
    int end = row_ptr[v + 1];
    float ax0 = 0.f, ay0 = 0.f, ax1 = 0.f, ay1 = 0.f;
    int e = beg;
    for (; e + 2 <= end; e += 2) {  // unroll-2 for load ILP
        int s0 = csr[e];
        int s1 = csr[e + 1];
        float2 t0 = ((const float2*)(feat + (size_t)s0 * N_FEAT))[lane];
        float2 t1 = ((const float2*)(feat + (size_t)s1 * N_FEAT))[lane];
        ax0 += t0.x; ay0 += t0.y;
        ax1 += t1.x; ay1 += t1.y;
    }
    if (e < end) {
        int s0 = csr[e];
        float2 t0 = ((const float2*)(feat + (size_t)s0 * N_FEAT))[lane];
        ax0 += t0.x; ay0 += t0.y;
    }
    int deg = end - beg;
    float inv = (deg > 0) ? 1.0f / (float)deg : 0.0f;  // deg==0 -> sum==0 -> 0 (matches clip)
    float2 r;
    r.x = (ax0 + ax1) * inv;
    r.y = (ay0 + ay1) * inv;
    ((float2*)(out + (size_t)v * N_FEAT))[lane] = r;
}

// h[64 nodes x 128] = relu(x@W1 + neigh@W2 + b). K=256 (two sources), BK=64 tiles.
// LDS: A-tile stored k-major [64k][64row] (16KB), W-tile [64k][128col] (32KB).
// Thread (ty=tid/32, tx=tid%32) owns rows ty*8..+7, cols tx*4..+3 -> acc[8][4].
__global__ __launch_bounds__(256) void gemm1_kernel(
    const float* __restrict__ x, const float* __restrict__ nb,
    const float* __restrict__ w1, const float* __restrict__ w2,
    const float* __restrict__ b, float* __restrict__ h, int n) {
    __shared__ float As[64][64];
    __shared__ float Ws[64][128];
    int tid = threadIdx.x;
    int ty = tid >> 5;   // 0..7
    int tx = tid & 31;   // 0..31
    int block_row = blockIdx.x * 64;
    float acc[8][4] = {};

    for (int kt = 0; kt < 4; ++kt) {
        const float* A = (kt < 2) ? x : nb;
        const float* W = (kt < 2) ? w1 : w2;
        int k0 = (kt & 1) * 64;
        // stage A (transpose to k-major): 1024 float4 loads / 256 threads = 4 each
        #pragma unroll
        for (int l = 0; l < 4; ++l) {
            int idx = l * 256 + tid;
            int row = idx & 63;
            int c4 = idx >> 6;  // 0..15
            int node = block_row + row;
            float4 val = make_float4(0.f, 0.f, 0.f, 0.f);
            if (node < n) val = *(const float4*)(A + (size_t)node * N_FEAT + k0 + c4 * 4);
            As[c4 * 4 + 0][row] = val.x;
            As[c4 * 4 + 1][row] = val.y;
            As[c4 * 4 + 2][row] = val.z;
            As[c4 * 4 + 3][row] = val.w;
        }
        // stage W: 2048 float4 / 256 threads = 8 each
        #pragma unroll
        for (int l = 0; l < 8; ++l) {
            int idx = l * 256 + tid;
            int kr = idx >> 5;  // 0..63
            int c4 = idx & 31;  // 0..31
            *(float4*)(&Ws[kr][c4 * 4]) = *(const float4*)(W + (size_t)(k0 + kr) * N_FEAT + c4 * 4);
        }
        __syncthreads();
        #pragma unroll 8
        for (int k = 0; k < 64; ++k) {
            float4 a0 = *(const float4*)(&As[k][ty * 8]);
            float4 a1 = *(const float4*)(&As[k][ty * 8 + 4]);
            float4 w = *(const float4*)(&Ws[k][tx * 4]);
            float av[8] = {a0.x, a0.y, a0.z, a0.w, a1.x, a1.y, a1.z, a1.w};
            #pragma unroll
            for (int i = 0; i < 8; ++i) {
                acc[i][0] += av[i] * w.x;
                acc[i][1] += av[i] * w.y;
                acc[i][2] += av[i] * w.z;
                acc[i][3] += av[i] * w.w;
            }
        }
        __syncthreads();
    }
    int col = tx * 4;
    float4 bias = *(const float4*)(b + col);
    #pragma unroll
    for (int i = 0; i < 8; ++i) {
        int node = block_row + ty * 8 + i;
        if (node < n) {
            float4 r;
            r.x = fmaxf(acc[i][0] + bias.x, 0.f);
            r.y = fmaxf(acc[i][1] + bias.y, 0.f);
            r.z = fmaxf(acc[i][2] + bias.z, 0.f);
            r.w = fmaxf(acc[i][3] + bias.w, 0.f);
            *(float4*)(h + (size_t)node * N_FEAT + col) = r;
        }
    }
}

// Layer 2 (K=128 -> 2 classes) + log_softmax. One wave per node, shuffle reduce.
__global__ void layer2_kernel(const float* __restrict__ h, const float* __restrict__ nb,
                              const float* __restrict__ ws, const float* __restrict__ wn,
                              const float* __restrict__ b, float* __restrict__ out, int n) {
    int v = blockIdx.x * 4 + (threadIdx.x >> 6);
    int lane = threadIdx.x & 63;
    if (v >= n) return;
    float2 hv = ((const float2*)(h + (size_t)v * N_FEAT))[lane];
    float2 nv = ((const float2*)(nb + (size_t)v * N_FEAT))[lane];
    // ws,[128][2] row-major: lane l covers rows 2l,2l+1 -> float4 {w[2l][0],w[2l][1],w[2l+1][0],w[2l+1][1]}
    float4 w0 = ((const float4*)ws)[lane];
    float4 w1 = ((const float4*)wn)[lane];
    float p0 = hv.x * w0.x + hv.y * w0.z + nv.x * w1.x + nv.y * w1.z;
    float p1 = hv.x * w0.y + hv.y * w0.w + nv.x * w1.y + nv.y * w1.w;
    #pragma unroll
    for (int off = 32; off > 0; off >>= 1) {
        p0 += __shfl_xor(p0, off);
        p1 += __shfl_xor(p1, off);
    }
    if (lane == 0) {
        float o0 = p0 + b[0];
        float o1 = p1 + b[1];
        float m = fmaxf(o0, o1);
        float lse = m + logf(expf(o0 - m) + expf(o1 - m));
        float2 r;
        r.x = o0 - lse;
        r.y = o1 - lse;
        *(float2*)(out + (size_t)v * 2) = r;
    }
}

extern "C" void kernel_launch(void* const* d_in, const int* in_sizes, int n_in,
                              void* d_out, int out_size, void* d_ws, size_t ws_size,
                              hipStream_t stream) {
    const float* x        = (const float*)d_in[0];
    const int*   src      = (const int*)d_in[1];
    const int*   dst      = (const int*)d_in[2];
    const float* w_self1  = (const float*)d_in[3];
    const float* w_neigh1 = (const float*)d_in[4];
    const float* b1       = (const float*)d_in[5];
    const float* w_self2  = (const float*)d_in[6];
    const float* w_neigh2 = (const float*)d_in[7];
    const float* b2       = (const float*)d_in[8];
    float* out = (float*)d_out;

    int N = in_sizes[0] / N_FEAT;
    int E = in_sizes[1];

    char* ws = (char*)d_ws;
    size_t off = 0;
    auto alloc = [&](size_t bytes) -> void* {
        void* p = ws + off;
        off += (bytes + 255) & ~(size_t)255;
        return p;
    };
    int*   deg     = (int*)alloc((size_t)N * 4);
    int*   cnt     = (int*)alloc((size_t)N * 4);
    int*   excl    = (int*)alloc((size_t)N * 4);
    int*   bsum    = (int*)alloc(4096);
    int*   row_ptr = (int*)alloc((size_t)(N + 1) * 4);
    int*   csr     = (int*)alloc((size_t)E * 4);
    float* neigh   = (float*)alloc((size_t)N * N_FEAT * 4);  // reused as neigh2
    float* h       = (float*)alloc((size_t)N * N_FEAT * 4);
    (void)ws_size; (void)n_in; (void)out_size;
    // total ws use ~110.4 MB

    hipMemsetAsync(deg, 0, (size_t)N * 4, stream);
    hipMemsetAsync(cnt, 0, (size_t)N * 4, stream);

    int NB = (N + 255) / 256;
    deg_kernel<<<(E + 255) / 256, 256, 0, stream>>>(dst, deg, E);
    scan_block<<<NB, 256, 0, stream>>>(deg, excl, bsum, N);
    scan_sums<<<1, 64, 0, stream>>>(bsum, NB);
    scan_add<<<NB, 256, 0, stream>>>(excl, bsum, row_ptr, N, E);
    scatter_kernel<<<(E + 255) / 256, 256, 0, stream>>>(src, dst, row_ptr, cnt, csr, E);

    aggregate_kernel<<<(N + 3) / 4, 256, 0, stream>>>(x, row_ptr, csr, neigh, N);
    gemm1_kernel<<<(N + 63) / 64, 256, 0, stream>>>(x, neigh, w_self1, w_neigh1, b1, h, N);
    aggregate_kernel<<<(N + 3) / 4, 256, 0, stream>>>(h, row_ptr, csr, neigh, N);
    layer2_kernel<<<(N + 3) / 4, 256, 0, stream>>>(h, neigh, w_self2, w_neigh2, b2, out, N);
}

// Round 2
// 527.783 us; speedup vs baseline: 1.2210x; 1.2210x over previous
//
#include <hip/hip_runtime.h>
#include <hip/hip_bf16.h>

// SAGE 2-layer forward, R2:
//   neigh1 = segment_mean(x[src] by dst); h = relu(x@Ws1 + neigh1@Wn1 + b1)
//   layer2 via linearity: z = h@Wn2 ([N,2]); out = log_softmax(h@Ws2 + segment_mean(z) + b2)
// R2 changes vs R1:
//   - aggregate #2 (819MB gather of h) replaced by 2-wide gather of z (12.8MB, L2-resident)
//   - aggregate #1 gathers bf16 copy of x (halves 819MB -> 410MB logical), fp32 accum
// CSR build (deg -> scan -> scatter) unchanged. gemm1 fp32 vector unchanged.

#define N_FEAT 128

__global__ void deg_kernel(const int* __restrict__ dst, int* __restrict__ deg, int E) {
    int e = blockIdx.x * 256 + threadIdx.x;
    if (e < E) atomicAdd(&deg[dst[e]], 1);
}

__global__ void scan_block(const int* __restrict__ deg, int* __restrict__ excl,
                           int* __restrict__ bsum, int n) {
    __shared__ int s[256];
    int tid = threadIdx.x;
    int i = blockIdx.x * 256 + tid;
    int v = (i < n) ? deg[i] : 0;
    int val = v;
    s[tid] = val;
    __syncthreads();
    for (int off = 1; off < 256; off <<= 1) {
        int t = (tid >= off) ? s[tid - off] : 0;
        __syncthreads();
        val += t;
        s[tid] = val;
        __syncthreads();
    }
    if (i < n) excl[i] = val - v;
    if (tid == 255) bsum[blockIdx.x] = val;
}

__global__ void scan_sums(int* __restrict__ bsum, int nb) {
    if (threadIdx.x == 0 && blockIdx.x == 0) {
        int acc = 0;
        for (int i = 0; i < nb; ++i) { int t = bsum[i]; bsum[i] = acc; acc += t; }
    }
}

__global__ void scan_add(const int* __restrict__ excl, const int* __restrict__ bsum,
                         int* __restrict__ row_ptr, int n, int E) {
    int i = blockIdx.x * 256 + threadIdx.x;
    if (i < n) row_ptr[i] = excl[i] + bsum[blockIdx.x];
    if (i == 0) row_ptr[n] = E;
}

__global__ void scatter_kernel(const int* __restrict__ src, const int* __restrict__ dst,
                               const int* __restrict__ row_ptr, int* __restrict__ cnt,
                               int* __restrict__ csr, int E) {
    int e = blockIdx.x * 256 + threadIdx.x;
    if (e < E) {
        int d = dst[e];
        int pos = row_ptr[d] + atomicAdd(&cnt[d], 1);
        csr[pos] = src[e];
    }
}

// x (fp32) -> bf16 bits, RNE. Grid-stride, float4 in / ushort4 out.
__global__ void to_bf16_kernel(const float* __restrict__ x, ushort* __restrict__ xb, int n4) {
    int i = blockIdx.x * 256 + threadIdx.x;
    int stride = gridDim.x * 256;
    for (; i < n4; i += stride) {
        float4 v = ((const float4*)x)[i];
        ushort4 r;
        r.x = __bfloat16_as_ushort(__float2bfloat16(v.x));
        r.y = __bfloat16_as_ushort(__float2bfloat16(v.y));
        r.z = __bfloat16_as_ushort(__float2bfloat16(v.z));
        r.w = __bfloat16_as_ushort(__float2bfloat16(v.w));
        ((ushort4*)xb)[i] = r;
    }
}

__device__ __forceinline__ float bf16_bits_to_f32(ushort u) {
    union { unsigned int i; float f; } c;
    c.i = ((unsigned int)u) << 16;
    return c.f;
}

// One wave per node; row is 256B of bf16; lane reads ushort2 (feats 2l, 2l+1).
// Accumulate fp32, write neigh fp32.
__global__ void aggregate_bf16_kernel(const ushort* __restrict__ xb,
                                      const int* __restrict__ row_ptr,
                                      const int* __restrict__ csr,
                                      float* __restrict__ out, int n) {
    int v = blockIdx.x * 4 + (threadIdx.x >> 6);
    int lane = threadIdx.x & 63;
    if (v >= n) return;
    int beg = row_ptr[v];
    int end = row_ptr[v + 1];
    float a0 = 0.f, b0 = 0.f, a1 = 0.f, b1 = 0.f;
    int e = beg;
    for (; e + 4 <= end; e += 4) {  // unroll-4 for load ILP (4B/lane loads)
        int s0 = csr[e], s1 = csr[e + 1], s2 = csr[e + 2], s3 = csr[e + 3];
        ushort2 t0 = ((const ushort2*)(xb + (size_t)s0 * N_FEAT))[lane];
        ushort2 t1 = ((const ushort2*)(xb + (size_t)s1 * N_FEAT))[lane];
        ushort2 t2 = ((const ushort2*)(xb + (size_t)s2 * N_FEAT))[lane];
        ushort2 t3 = ((const ushort2*)(xb + (size_t)s3 * N_FEAT))[lane];
        a0 += bf16_bits_to_f32(t0.x); b0 += bf16_bits_to_f32(t0.y);
        a1 += bf16_bits_to_f32(t1.x); b1 += bf16_bits_to_f32(t1.y);
        a0 += bf16_bits_to_f32(t2.x); b0 += bf16_bits_to_f32(t2.y);
        a1 += bf16_bits_to_f32(t3.x); b1 += bf16_bits_to_f32(t3.y);
    }
    for (; e < end; ++e) {
        int s0 = csr[e];
        ushort2 t0 = ((const ushort2*)(xb + (size_t)s0 * N_FEAT))[lane];
        a0 += bf16_bits_to_f32(t0.x); b0 += bf16_bits_to_f32(t0.y);
    }
    int deg = end - beg;
    float inv = (deg > 0) ? 1.0f / (float)deg : 0.0f;
    float2 r;
    r.x = (a0 + a1) * inv;
    r.y = (b0 + b1) * inv;
    ((float2*)(out + (size_t)v * N_FEAT))[lane] = r;
}

// h[64 nodes x 128] = relu(x@W1 + neigh@W2 + b). K=256 (two sources), BK=64 tiles.
__global__ __launch_bounds__(256) void gemm1_kernel(
    const float* __restrict__ x, const float* __restrict__ nb,
    const float* __restrict__ w1, const float* __restrict__ w2,
    const float* __restrict__ b, float* __restrict__ h, int n) {
    __shared__ float As[64][64];
    __shared__ float Ws[64][128];
    int tid = threadIdx.x;
    int ty = tid >> 5;   // 0..7
    int tx = tid & 31;   // 0..31
    int block_row = blockIdx.x * 64;
    float acc[8][4] = {};

    for (int kt = 0; kt < 4; ++kt) {
        const float* A = (kt < 2) ? x : nb;
        const float* W = (kt < 2) ? w1 : w2;
        int k0 = (kt & 1) * 64;
        #pragma unroll
        for (int l = 0; l < 4; ++l) {
            int idx = l * 256 + tid;
            int row = idx & 63;
            int c4 = idx >> 6;
            int node = block_row + row;
            float4 val = make_float4(0.f, 0.f, 0.f, 0.f);
            if (node < n) val = *(const float4*)(A + (size_t)node * N_FEAT + k0 + c4 * 4);
            As[c4 * 4 + 0][row] = val.x;
            As[c4 * 4 + 1][row] = val.y;
            As[c4 * 4 + 2][row] = val.z;
            As[c4 * 4 + 3][row] = val.w;
        }
        #pragma unroll
        for (int l = 0; l < 8; ++l) {
            int idx = l * 256 + tid;
            int kr = idx >> 5;
            int c4 = idx & 31;
            *(float4*)(&Ws[kr][c4 * 4]) = *(const float4*)(W + (size_t)(k0 + kr) * N_FEAT + c4 * 4);
        }
        __syncthreads();
        #pragma unroll 8
        for (int k = 0; k < 64; ++k) {
            float4 a0 = *(const float4*)(&As[k][ty * 8]);
            float4 a1 = *(const float4*)(&As[k][ty * 8 + 4]);
            float4 w = *(const float4*)(&Ws[k][tx * 4]);
            float av[8] = {a0.x, a0.y, a0.z, a0.w, a1.x, a1.y, a1.z, a1.w};
            #pragma unroll
            for (int i = 0; i < 8; ++i) {
                acc[i][0] += av[i] * w.x;
                acc[i][1] += av[i] * w.y;
                acc[i][2] += av[i] * w.z;
                acc[i][3] += av[i] * w.w;
            }
        }
        __syncthreads();
    }
    int col = tx * 4;
    float4 bias = *(const float4*)(b + col);
    #pragma unroll
    for (int i = 0; i < 8; ++i) {
        int node = block_row + ty * 8 + i;
        if (node < n) {
            float4 r;
            r.x = fmaxf(acc[i][0] + bias.x, 0.f);
            r.y = fmaxf(acc[i][1] + bias.y, 0.f);
            r.z = fmaxf(acc[i][2] + bias.z, 0.f);
            r.w = fmaxf(acc[i][3] + bias.w, 0.f);
            *(float4*)(h + (size_t)node * N_FEAT + col) = r;
        }
    }
}

// Layer-2 part A: per node v, s[v] = h[v]@Ws2 (no bias), z[v] = h[v]@Wn2.
// One wave per node; shuffle reduce 4 scalars.
__global__ void layer2a_kernel(const float* __restrict__ h,
                               const float* __restrict__ ws, const float* __restrict__ wn,
                               float* __restrict__ s_out, float* __restrict__ z_out, int n) {
    int v = blockIdx.x * 4 + (threadIdx.x >> 6);
    int lane = threadIdx.x & 63;
    if (v >= n) return;
    float2 hv = ((const float2*)(h + (size_t)v * N_FEAT))[lane];
    // ws [128][2] row-major: lane l covers rows 2l,2l+1 -> float4 {w[2l][0],w[2l][1],w[2l+1][0],w[2l+1][1]}
    float4 w0 = ((const float4*)ws)[lane];
    float4 w1 = ((const float4*)wn)[lane];
    float p0 = hv.x * w0.x + hv.y * w0.z;
    float p1 = hv.x * w0.y + hv.y * w0.w;
    float q0 = hv.x * w1.x + hv.y * w1.z;
    float q1 = hv.x * w1.y + hv.y * w1.w;
    #pragma unroll
    for (int off = 32; off > 0; off >>= 1) {
        p0 += __shfl_xor(p0, off);
        p1 += __shfl_xor(p1, off);
        q0 += __shfl_xor(q0, off);
        q1 += __shfl_xor(q1, off);
    }
    if (lane == 0) {
        ((float2*)s_out)[v] = make_float2(p0, p1);
        ((float2*)z_out)[v] = make_float2(q0, q1);
    }
}

// Layer-2 part B: per node (one thread), aggregate z over in-edges (z is 0.8MB,
// L2-resident), add self term + bias, log_softmax over 2 classes, write out.
__global__ void layer2b_kernel(const float* __restrict__ s_in, const float* __restrict__ z,
                               const int* __restrict__ row_ptr, const int* __restrict__ csr,
                               const float* __restrict__ b, float* __restrict__ out, int n) {
    int v = blockIdx.x * 256 + threadIdx.x;
    if (v >= n) return;
    int beg = row_ptr[v];
    int end = row_ptr[v + 1];
    float a0 = 0.f, a1 = 0.f, c0 = 0.f, c1 = 0.f;
    int e = beg;
    for (; e + 2 <= end; e += 2) {
        float2 t0 = ((const float2*)z)[csr[e]];
        float2 t1 = ((const float2*)z)[csr[e + 1]];
        a0 += t0.x; a1 += t0.y;
        c0 += t1.x; c1 += t1.y;
    }
    if (e < end) {
        float2 t0 = ((const float2*)z)[csr[e]];
        a0 += t0.x; a1 += t0.y;
    }
    int deg = end - beg;
    float inv = (deg > 0) ? 1.0f / (float)deg : 0.0f;
    float2 sv = ((const float2*)s_in)[v];
    float o0 = sv.x + (a0 + c0) * inv + b[0];
    float o1 = sv.y + (a1 + c1) * inv + b[1];
    float m = fmaxf(o0, o1);
    float lse = m + logf(expf(o0 - m) + expf(o1 - m));
    ((float2*)out)[v] = make_float2(o0 - lse, o1 - lse);
}

extern "C" void kernel_launch(void* const* d_in, const int* in_sizes, int n_in,
                              void* d_out, int out_size, void* d_ws, size_t ws_size,
                              hipStream_t stream) {
    const float* x        = (const float*)d_in[0];
    const int*   src      = (const int*)d_in[1];
    const int*   dst      = (const int*)d_in[2];
    const float* w_self1  = (const float*)d_in[3];
    const float* w_neigh1 = (const float*)d_in[4];
    const float* b1       = (const float*)d_in[5];
    const float* w_self2  = (const float*)d_in[6];
    const float* w_neigh2 = (const float*)d_in[7];
    const float* b2       = (const float*)d_in[8];
    float* out = (float*)d_out;

    int N = in_sizes[0] / N_FEAT;
    int E = in_sizes[1];

    char* ws = (char*)d_ws;
    size_t off = 0;
    auto alloc = [&](size_t bytes) -> void* {
        void* p = ws + off;
        off += (bytes + 255) & ~(size_t)255;
        return p;
    };
    int*    deg     = (int*)alloc((size_t)N * 4);
    int*    cnt     = (int*)alloc((size_t)N * 4);
    int*    excl    = (int*)alloc((size_t)N * 4);
    int*    bsum    = (int*)alloc(4096);
    int*    row_ptr = (int*)alloc((size_t)(N + 1) * 4);
    int*    csr     = (int*)alloc((size_t)E * 4);
    ushort* xb      = (ushort*)alloc((size_t)N * N_FEAT * 2);
    float*  neigh   = (float*)alloc((size_t)N * N_FEAT * 4);
    float*  h       = (float*)alloc((size_t)N * N_FEAT * 4);
    float*  s_buf   = (float*)alloc((size_t)N * 2 * 4);
    float*  z_buf   = (float*)alloc((size_t)N * 2 * 4);
    (void)ws_size; (void)n_in; (void)out_size;

    hipMemsetAsync(deg, 0, (size_t)N * 4, stream);
    hipMemsetAsync(cnt, 0, (size_t)N * 4, stream);

    int NB = (N + 255) / 256;
    deg_kernel<<<(E + 255) / 256, 256, 0, stream>>>(dst, deg, E);
    scan_block<<<NB, 256, 0, stream>>>(deg, excl, bsum, N);
    scan_sums<<<1, 64, 0, stream>>>(bsum, NB);
    scan_add<<<NB, 256, 0, stream>>>(excl, bsum, row_ptr, N, E);
    scatter_kernel<<<(E + 255) / 256, 256, 0, stream>>>(src, dst, row_ptr, cnt, csr, E);

    to_bf16_kernel<<<1024, 256, 0, stream>>>(x, xb, N * N_FEAT / 4);
    aggregate_bf16_kernel<<<(N + 3) / 4, 256, 0, stream>>>(xb, row_ptr, csr, neigh, N);
    gemm1_kernel<<<(N + 63) / 64, 256, 0, stream>>>(x, neigh, w_self1, w_neigh1, b1, h, N);
    layer2a_kernel<<<(N + 3) / 4, 256, 0, stream>>>(h, w_self2, w_neigh2, s_buf, z_buf, N);
    layer2b_kernel<<<NB, 256, 0, stream>>>(s_buf, z_buf, row_ptr, csr, b2, out, N);
}

// Round 3
// 393.594 us; speedup vs baseline: 1.6373x; 1.3409x over previous
//
#include <hip/hip_runtime.h>
#include <hip/hip_bf16.h>

// SAGE 2-layer forward, R3:
//   neigh1 = segment_mean(x[src]); h = relu(x@Ws1 + neigh1@Wn1 + b1)   [bf16 MFMA]
//   z = h@Wn2, s = h@Ws2; out = log_softmax(s + segment_mean(z) + b2)
// R3 changes vs R2:
//   - gemm1 -> v_mfma_f32_32x32x16_bf16, 128x128 tile, K=256, fp32 accum
//   - neigh + h stored bf16 (halves gemm/layer2a traffic)
//   - scan_sums: serial 1-thread loop (-~40us latency) -> single-block parallel scan

#define N_FEAT 128

typedef __attribute__((ext_vector_type(8))) short short8;
typedef __attribute__((ext_vector_type(8))) unsigned short ushort8_t;
typedef __attribute__((ext_vector_type(16))) float f32x16;

__global__ void deg_kernel(const int* __restrict__ dst, int* __restrict__ deg, int E) {
    int e = blockIdx.x * 256 + threadIdx.x;
    if (e < E) atomicAdd(&deg[dst[e]], 1);
}

__global__ void scan_block(const int* __restrict__ deg, int* __restrict__ excl,
                           int* __restrict__ bsum, int n) {
    __shared__ int s[256];
    int tid = threadIdx.x;
    int i = blockIdx.x * 256 + tid;
    int v = (i < n) ? deg[i] : 0;
    int val = v;
    s[tid] = val;
    __syncthreads();
    for (int off = 1; off < 256; off <<= 1) {
        int t = (tid >= off) ? s[tid - off] : 0;
        __syncthreads();
        val += t;
        s[tid] = val;
        __syncthreads();
    }
    if (i < n) excl[i] = val - v;
    if (tid == 255) bsum[blockIdx.x] = val;
}

// Parallel exclusive scan of block sums (nb <= 512). Single block.
__global__ void scan_sums_par(int* __restrict__ bsum, int nb) {
    __shared__ int s[512];
    int tid = threadIdx.x;
    int v = (tid < nb) ? bsum[tid] : 0;
    int val = v;
    s[tid] = val;
    __syncthreads();
    for (int off = 1; off < 512; off <<= 1) {
        int t = (tid >= off) ? s[tid - off] : 0;
        __syncthreads();
        val += t;
        s[tid] = val;
        __syncthreads();
    }
    if (tid < nb) bsum[tid] = val - v;  // exclusive
}

__global__ void scan_add(const int* __restrict__ excl, const int* __restrict__ bsum,
                         int* __restrict__ row_ptr, int n, int E) {
    int i = blockIdx.x * 256 + threadIdx.x;
    if (i < n) row_ptr[i] = excl[i] + bsum[blockIdx.x];
    if (i == 0) row_ptr[n] = E;
}

__global__ void scatter_kernel(const int* __restrict__ src, const int* __restrict__ dst,
                               const int* __restrict__ row_ptr, int* __restrict__ cnt,
                               int* __restrict__ csr, int E) {
    int e = blockIdx.x * 256 + threadIdx.x;
    if (e < E) {
        int d = dst[e];
        int pos = row_ptr[d] + atomicAdd(&cnt[d], 1);
        csr[pos] = src[e];
    }
}

__global__ void to_bf16_kernel(const float* __restrict__ x, ushort* __restrict__ xb, int n4) {
    int i = blockIdx.x * 256 + threadIdx.x;
    int stride = gridDim.x * 256;
    for (; i < n4; i += stride) {
        float4 v = ((const float4*)x)[i];
        ushort4 r;
        r.x = __bfloat16_as_ushort(__float2bfloat16(v.x));
        r.y = __bfloat16_as_ushort(__float2bfloat16(v.y));
        r.z = __bfloat16_as_ushort(__float2bfloat16(v.z));
        r.w = __bfloat16_as_ushort(__float2bfloat16(v.w));
        ((ushort4*)xb)[i] = r;
    }
}

// Build Wt[n=128][k=256] bf16 from w_self1 (k 0..127) and w_neigh1 (k 128..255),
// both [k][n] fp32 row-major. 32768 threads, trivial.
__global__ void prep_weights_kernel(const float* __restrict__ w1, const float* __restrict__ w2,
                                    ushort* __restrict__ wt) {
    int id = blockIdx.x * 256 + threadIdx.x;
    if (id >= 128 * 256) return;
    int nn = id >> 8;    // 0..127
    int k = id & 255;    // 0..255
    float v = (k < 128) ? w1[k * 128 + nn] : w2[(k - 128) * 128 + nn];
    wt[nn * 256 + k] = __bfloat16_as_ushort(__float2bfloat16(v));
}

__device__ __forceinline__ float bf16_bits_to_f32(ushort u) {
    union { unsigned int i; float f; } c;
    c.i = ((unsigned int)u) << 16;
    return c.f;
}

// One wave per node; bf16 gather, fp32 accum, bf16 output.
__global__ void aggregate_bf16_kernel(const ushort* __restrict__ xb,
                                      const int* __restrict__ row_ptr,
                                      const int* __restrict__ csr,
                                      ushort* __restrict__ out, int n) {
    int v = blockIdx.x * 4 + (threadIdx.x >> 6);
    int lane = threadIdx.x & 63;
    if (v >= n) return;
    int beg = row_ptr[v];
    int end = row_ptr[v + 1];
    float a0 = 0.f, b0 = 0.f, a1 = 0.f, b1 = 0.f;
    int e = beg;
    for (; e + 4 <= end; e += 4) {
        int s0 = csr[e], s1 = csr[e + 1], s2 = csr[e + 2], s3 = csr[e + 3];
        ushort2 t0 = ((const ushort2*)(xb + (size_t)s0 * N_FEAT))[lane];
        ushort2 t1 = ((const ushort2*)(xb + (size_t)s1 * N_FEAT))[lane];
        ushort2 t2 = ((const ushort2*)(xb + (size_t)s2 * N_FEAT))[lane];
        ushort2 t3 = ((const ushort2*)(xb + (size_t)s3 * N_FEAT))[lane];
        a0 += bf16_bits_to_f32(t0.x); b0 += bf16_bits_to_f32(t0.y);
        a1 += bf16_bits_to_f32(t1.x); b1 += bf16_bits_to_f32(t1.y);
        a0 += bf16_bits_to_f32(t2.x); b0 += bf16_bits_to_f32(t2.y);
        a1 += bf16_bits_to_f32(t3.x); b1 += bf16_bits_to_f32(t3.y);
    }
    for (; e < end; ++e) {
        int s0 = csr[e];
        ushort2 t0 = ((const ushort2*)(xb + (size_t)s0 * N_FEAT))[lane];
        a0 += bf16_bits_to_f32(t0.x); b0 += bf16_bits_to_f32(t0.y);
    }
    int deg = end - beg;
    float inv = (deg > 0) ? 1.0f / (float)deg : 0.0f;
    ushort2 r;
    r.x = __bfloat16_as_ushort(__float2bfloat16((a0 + a1) * inv));
    r.y = __bfloat16_as_ushort(__float2bfloat16((b0 + b1) * inv));
    ((ushort2*)(out + (size_t)v * N_FEAT))[lane] = r;
}

// h[128 nodes x 128] = relu([x|neigh] @ Wt^T + b), bf16 MFMA, fp32 accum.
// Block: 256 threads = 4 waves. Wave w -> rows 32w..32w+31, all 128 cols (4 col-tiles).
// K=256 in 4 chunks of 64; LDS tiles [128][72] bf16 (pad 8 -> stride 144B, <=2-way banks).
// A-frag (32x32x16): A[m=lane&31][k=(lane>>5)*8+j]; B-frag: B[k][n=lane&31] same k split.
// C/D: col=lane&31, row=(reg&3)+8*(reg>>2)+4*(lane>>5)  [measured m74/m101].
__global__ __launch_bounds__(256) void gemm1_mfma_kernel(
    const ushort* __restrict__ xb, const ushort* __restrict__ nbb,
    const ushort* __restrict__ wt, const float* __restrict__ b,
    ushort* __restrict__ h, int n) {
    __shared__ ushort As[128 * 72];
    __shared__ ushort Bs[128 * 72];
    int tid = threadIdx.x;
    int wave = tid >> 6;
    int lane = tid & 63;
    int m = lane & 31;
    int half = lane >> 5;
    int block_row = blockIdx.x * 128;

    f32x16 acc[4];
    #pragma unroll
    for (int t = 0; t < 4; ++t)
        #pragma unroll
        for (int i = 0; i < 16; ++i) acc[t][i] = 0.0f;

    for (int kc = 0; kc < 4; ++kc) {
        const ushort* A = (kc < 2) ? xb : nbb;
        int k0 = (kc & 1) * 64;
        // stage A: 128 rows x 64 bf16 = 1024 x 16B pieces / 256 threads = 4 each
        #pragma unroll
        for (int l = 0; l < 4; ++l) {
            int idx = l * 256 + tid;
            int r = idx >> 3;
            int p = idx & 7;
            int node = block_row + r;
            ushort8_t v;
            if (node < n) {
                v = *(const ushort8_t*)(A + (size_t)node * N_FEAT + k0 + p * 8);
            } else {
                #pragma unroll
                for (int q = 0; q < 8; ++q) v[q] = 0;
            }
            *(ushort8_t*)(&As[r * 72 + p * 8]) = v;
        }
        // stage B: Wt[col][kc*64 .. +63]
        #pragma unroll
        for (int l = 0; l < 4; ++l) {
            int idx = l * 256 + tid;
            int c = idx >> 3;
            int p = idx & 7;
            ushort8_t v = *(const ushort8_t*)(wt + (size_t)c * 256 + kc * 64 + p * 8);
            *(ushort8_t*)(&Bs[c * 72 + p * 8]) = v;
        }
        __syncthreads();
        #pragma unroll
        for (int ks = 0; ks < 4; ++ks) {
            int koff = ks * 16 + half * 8;
            short8 a = *(const short8*)(&As[(32 * wave + m) * 72 + koff]);
            short8 bf0 = *(const short8*)(&Bs[(0 * 32 + m) * 72 + koff]);
            short8 bf1 = *(const short8*)(&Bs[(1 * 32 + m) * 72 + koff]);
            short8 bf2 = *(const short8*)(&Bs[(2 * 32 + m) * 72 + koff]);
            short8 bf3 = *(const short8*)(&Bs[(3 * 32 + m) * 72 + koff]);
            acc[0] = __builtin_amdgcn_mfma_f32_32x32x16_bf16(a, bf0, acc[0], 0, 0, 0);
            acc[1] = __builtin_amdgcn_mfma_f32_32x32x16_bf16(a, bf1, acc[1], 0, 0, 0);
            acc[2] = __builtin_amdgcn_mfma_f32_32x32x16_bf16(a, bf2, acc[2], 0, 0, 0);
            acc[3] = __builtin_amdgcn_mfma_f32_32x32x16_bf16(a, bf3, acc[3], 0, 0, 0);
        }
        __syncthreads();
    }
    #pragma unroll
    for (int t = 0; t < 4; ++t) {
        int col = t * 32 + m;
        float bias = b[col];
        #pragma unroll
        for (int reg = 0; reg < 16; ++reg) {
            int rowin = (reg & 3) + 8 * (reg >> 2) + 4 * half;
            int node = block_row + 32 * wave + rowin;
            if (node < n) {
                float v = fmaxf(acc[t][reg] + bias, 0.0f);
                h[(size_t)node * N_FEAT + col] = __bfloat16_as_ushort(__float2bfloat16(v));
            }
        }
    }
}

// Layer-2 part A: s[v] = h[v]@Ws2, z[v] = h[v]@Wn2 (h is bf16). Wave per node.
__global__ void layer2a_kernel(const ushort* __restrict__ h,
                               const float* __restrict__ ws, const float* __restrict__ wn,
                               float* __restrict__ s_out, float* __restrict__ z_out, int n) {
    int v = blockIdx.x * 4 + (threadIdx.x >> 6);
    int lane = threadIdx.x & 63;
    if (v >= n) return;
    ushort2 hb = ((const ushort2*)(h + (size_t)v * N_FEAT))[lane];
    float hx = bf16_bits_to_f32(hb.x);
    float hy = bf16_bits_to_f32(hb.y);
    float4 w0 = ((const float4*)ws)[lane];
    float4 w1 = ((const float4*)wn)[lane];
    float p0 = hx * w0.x + hy * w0.z;
    float p1 = hx * w0.y + hy * w0.w;
    float q0 = hx * w1.x + hy * w1.z;
    float q1 = hx * w1.y + hy * w1.w;
    #pragma unroll
    for (int off = 32; off > 0; off >>= 1) {
        p0 += __shfl_xor(p0, off);
        p1 += __shfl_xor(p1, off);
        q0 += __shfl_xor(q0, off);
        q1 += __shfl_xor(q1, off);
    }
    if (lane == 0) {
        ((float2*)s_out)[v] = make_float2(p0, p1);
        ((float2*)z_out)[v] = make_float2(q0, q1);
    }
}

// Layer-2 part B: aggregate z (L2-resident, 0.8MB), add self + bias, log_softmax.
__global__ void layer2b_kernel(const float* __restrict__ s_in, const float* __restrict__ z,
                               const int* __restrict__ row_ptr, const int* __restrict__ csr,
                               const float* __restrict__ b, float* __restrict__ out, int n) {
    int v = blockIdx.x * 256 + threadIdx.x;
    if (v >= n) return;
    int beg = row_ptr[v];
    int end = row_ptr[v + 1];
    float a0 = 0.f, a1 = 0.f, c0 = 0.f, c1 = 0.f;
    int e = beg;
    for (; e + 2 <= end; e += 2) {
        float2 t0 = ((const float2*)z)[csr[e]];
        float2 t1 = ((const float2*)z)[csr[e + 1]];
        a0 += t0.x; a1 += t0.y;
        c0 += t1.x; c1 += t1.y;
    }
    if (e < end) {
        float2 t0 = ((const float2*)z)[csr[e]];
        a0 += t0.x; a1 += t0.y;
    }
    int deg = end - beg;
    float inv = (deg > 0) ? 1.0f / (float)deg : 0.0f;
    float2 sv = ((const float2*)s_in)[v];
    float o0 = sv.x + (a0 + c0) * inv + b[0];
    float o1 = sv.y + (a1 + c1) * inv + b[1];
    float mx = fmaxf(o0, o1);
    float lse = mx + logf(expf(o0 - mx) + expf(o1 - mx));
    ((float2*)out)[v] = make_float2(o0 - lse, o1 - lse);
}

extern "C" void kernel_launch(void* const* d_in, const int* in_sizes, int n_in,
                              void* d_out, int out_size, void* d_ws, size_t ws_size,
                              hipStream_t stream) {
    const float* x        = (const float*)d_in[0];
    const int*   src      = (const int*)d_in[1];
    const int*   dst      = (const int*)d_in[2];
    const float* w_self1  = (const float*)d_in[3];
    const float* w_neigh1 = (const float*)d_in[4];
    const float* b1       = (const float*)d_in[5];
    const float* w_self2  = (const float*)d_in[6];
    const float* w_neigh2 = (const float*)d_in[7];
    const float* b2       = (const float*)d_in[8];
    float* out = (float*)d_out;

    int N = in_sizes[0] / N_FEAT;
    int E = in_sizes[1];

    char* ws = (char*)d_ws;
    size_t off = 0;
    auto alloc = [&](size_t bytes) -> void* {
        void* p = ws + off;
        off += (bytes + 255) & ~(size_t)255;
        return p;
    };
    int*    deg     = (int*)alloc((size_t)N * 4);
    int*    cnt     = (int*)alloc((size_t)N * 4);
    int*    excl    = (int*)alloc((size_t)N * 4);
    int*    bsum    = (int*)alloc(4096);
    int*    row_ptr = (int*)alloc((size_t)(N + 1) * 4);
    int*    csr     = (int*)alloc((size_t)E * 4);
    ushort* xb      = (ushort*)alloc((size_t)N * N_FEAT * 2);
    ushort* nbb     = (ushort*)alloc((size_t)N * N_FEAT * 2);
    ushort* h       = (ushort*)alloc((size_t)N * N_FEAT * 2);
    ushort* wt      = (ushort*)alloc((size_t)128 * 256 * 2);
    float*  s_buf   = (float*)alloc((size_t)N * 2 * 4);
    float*  z_buf   = (float*)alloc((size_t)N * 2 * 4);
    (void)ws_size; (void)n_in; (void)out_size;

    hipMemsetAsync(deg, 0, (size_t)N * 4, stream);
    hipMemsetAsync(cnt, 0, (size_t)N * 4, stream);

    int NB = (N + 255) / 256;  // 391 <= 512 for scan_sums_par
    deg_kernel<<<(E + 255) / 256, 256, 0, stream>>>(dst, deg, E);
    scan_block<<<NB, 256, 0, stream>>>(deg, excl, bsum, N);
    scan_sums_par<<<1, 512, 0, stream>>>(bsum, NB);
    scan_add<<<NB, 256, 0, stream>>>(excl, bsum, row_ptr, N, E);
    scatter_kernel<<<(E + 255) / 256, 256, 0, stream>>>(src, dst, row_ptr, cnt, csr, E);

    to_bf16_kernel<<<1024, 256, 0, stream>>>(x, xb, N * N_FEAT / 4);
    prep_weights_kernel<<<(128 * 256 + 255) / 256, 256, 0, stream>>>(w_self1, w_neigh1, wt);
    aggregate_bf16_kernel<<<(N + 3) / 4, 256, 0, stream>>>(xb, row_ptr, csr, nbb, N);
    gemm1_mfma_kernel<<<(N + 127) / 128, 256, 0, stream>>>(xb, nbb, wt, b1, h, N);
    layer2a_kernel<<<(N + 3) / 4, 256, 0, stream>>>(h, w_self2, w_neigh2, s_buf, z_buf, N);
    layer2b_kernel<<<NB, 256, 0, stream>>>(s_buf, z_buf, row_ptr, csr, b2, out, N);
}

// Round 4
// 337.874 us; speedup vs baseline: 1.9074x; 1.1649x over previous
//
#include <hip/hip_runtime.h>
#include <hip/hip_bf16.h>

// SAGE 2-layer forward, R4:
//   neigh1 = segment_mean(x[src]); h = relu(x@Ws1 + neigh1@Wn1 + b1)   [bf16 MFMA]
//   z = h@Wn2, s = h@Ws2; out = log_softmax(s + segment_mean(z) + b2)
// R4 changes vs R3:
//   - CSR build rewritten: atomic scatter (107MB partial-line writes, ~120us) ->
//     2-level binning: bucket_scatter (dst>>7, 8-way XCD stripe, sequential u32 writes)
//     + per-bucket LDS counting sort (build_csr). Edges packed (dst&127)<<20|src.

#define N_FEAT 128
#define BKT_SHIFT 7          // 128 nodes per bucket
#define BKT_NODES 128
#define STRIPES 8
#define SCAP 512             // capacity per (bucket,stripe); mean 256, ~16 sigma head
#define BCAP (STRIPES * SCAP)

typedef __attribute__((ext_vector_type(8))) short short8;
typedef __attribute__((ext_vector_type(8))) unsigned short ushort8_t;
typedef __attribute__((ext_vector_type(16))) float f32x16;

// Pass 1: bin edges by dst bucket; stripe by blockIdx&7 (~XCD) for write locality.
__global__ void bucket_scatter_kernel(const int* __restrict__ src, const int* __restrict__ dst,
                                      int* __restrict__ cnt2, unsigned* __restrict__ buf, int E) {
    int e = blockIdx.x * 256 + threadIdx.x;
    if (e >= E) return;
    int d = dst[e];
    int b = d >> BKT_SHIFT;
    int stripe = blockIdx.x & (STRIPES - 1);
    int pos = atomicAdd(&cnt2[b * STRIPES + stripe], 1);
    buf[(size_t)b * BCAP + stripe * SCAP + pos] =
        ((unsigned)(d & (BKT_NODES - 1)) << 20) | (unsigned)src[e];
}

// Exclusive scan of per-bucket totals (nbk <= 1024). Also seeds row_ptr[N]=E.
__global__ void bucket_scan_kernel(const int* __restrict__ cnt2, int* __restrict__ bucket_start,
                                   int* __restrict__ row_ptr, int nbk, int N, int E) {
    __shared__ int s[1024];
    int tid = threadIdx.x;
    int tot = 0;
    if (tid < nbk) {
        #pragma unroll
        for (int k = 0; k < STRIPES; ++k) tot += cnt2[tid * STRIPES + k];
    }
    int val = tot;
    s[tid] = val;
    __syncthreads();
    for (int off = 1; off < 1024; off <<= 1) {
        int t = (tid >= off) ? s[tid - off] : 0;
        __syncthreads();
        val += t;
        s[tid] = val;
        __syncthreads();
    }
    if (tid < nbk) bucket_start[tid] = val - tot;
    if (tid == 0) row_ptr[N] = E;
}

// Pass 2: one block per bucket. LDS histogram over 128 local dst bins -> scan ->
// row_ptr (coalesced) -> cursor scatter of src into contiguous csr segment.
__global__ __launch_bounds__(256) void build_csr_kernel(
    const unsigned* __restrict__ buf, const int* __restrict__ cnt2,
    const int* __restrict__ bucket_start, int* __restrict__ row_ptr,
    int* __restrict__ csr, int N) {
    __shared__ int hist[BKT_NODES];
    __shared__ int scanb[BKT_NODES];
    __shared__ int nseg[STRIPES];
    int b = blockIdx.x;
    int tid = threadIdx.x;
    if (tid < STRIPES) nseg[tid] = cnt2[b * STRIPES + tid];
    if (tid < BKT_NODES) hist[tid] = 0;
    __syncthreads();
    size_t base_buf = (size_t)b * BCAP;
    for (int sg = 0; sg < STRIPES; ++sg) {
        int nl = nseg[sg];
        for (int e = tid; e < nl; e += 256) {
            unsigned p = buf[base_buf + sg * SCAP + e];
            atomicAdd(&hist[p >> 20], 1);
        }
    }
    __syncthreads();
    // exclusive scan of hist
    int v = (tid < BKT_NODES) ? hist[tid] : 0;
    int val = v;
    if (tid < BKT_NODES) scanb[tid] = val;
    __syncthreads();
    for (int off = 1; off < BKT_NODES; off <<= 1) {
        int t = (tid >= off && tid < BKT_NODES) ? scanb[tid - off] : 0;
        __syncthreads();
        if (tid < BKT_NODES) { val += t; scanb[tid] = val; }
        __syncthreads();
    }
    int base = bucket_start[b];
    int node = b * BKT_NODES + tid;
    if (tid < BKT_NODES && node < N) row_ptr[node] = base + (val - v);
    if (tid < BKT_NODES) hist[tid] = val - v;  // reuse as cursors
    __syncthreads();
    for (int sg = 0; sg < STRIPES; ++sg) {
        int nl = nseg[sg];
        for (int e = tid; e < nl; e += 256) {
            unsigned p = buf[base_buf + sg * SCAP + e];
            int bin = p >> 20;
            int ofs = atomicAdd(&hist[bin], 1);
            csr[base + ofs] = (int)(p & 0xFFFFF);
        }
    }
}

__global__ void to_bf16_kernel(const float* __restrict__ x, ushort* __restrict__ xb, int n4) {
    int i = blockIdx.x * 256 + threadIdx.x;
    int stride = gridDim.x * 256;
    for (; i < n4; i += stride) {
        float4 v = ((const float4*)x)[i];
        ushort4 r;
        r.x = __bfloat16_as_ushort(__float2bfloat16(v.x));
        r.y = __bfloat16_as_ushort(__float2bfloat16(v.y));
        r.z = __bfloat16_as_ushort(__float2bfloat16(v.z));
        r.w = __bfloat16_as_ushort(__float2bfloat16(v.w));
        ((ushort4*)xb)[i] = r;
    }
}

// Build Wt[n=128][k=256] bf16 from w_self1 (k 0..127) / w_neigh1 (k 128..255), both [k][n] fp32.
__global__ void prep_weights_kernel(const float* __restrict__ w1, const float* __restrict__ w2,
                                    ushort* __restrict__ wt) {
    int id = blockIdx.x * 256 + threadIdx.x;
    if (id >= 128 * 256) return;
    int nn = id >> 8;
    int k = id & 255;
    float v = (k < 128) ? w1[k * 128 + nn] : w2[(k - 128) * 128 + nn];
    wt[nn * 256 + k] = __bfloat16_as_ushort(__float2bfloat16(v));
}

__device__ __forceinline__ float bf16_bits_to_f32(ushort u) {
    union { unsigned int i; float f; } c;
    c.i = ((unsigned int)u) << 16;
    return c.f;
}

// One wave per node; bf16 gather, fp32 accum, bf16 output.
__global__ void aggregate_bf16_kernel(const ushort* __restrict__ xb,
                                      const int* __restrict__ row_ptr,
                                      const int* __restrict__ csr,
                                      ushort* __restrict__ out, int n) {
    int v = blockIdx.x * 4 + (threadIdx.x >> 6);
    int lane = threadIdx.x & 63;
    if (v >= n) return;
    int beg = row_ptr[v];
    int end = row_ptr[v + 1];
    float a0 = 0.f, b0 = 0.f, a1 = 0.f, b1 = 0.f;
    int e = beg;
    for (; e + 4 <= end; e += 4) {
        int s0 = csr[e], s1 = csr[e + 1], s2 = csr[e + 2], s3 = csr[e + 3];
        ushort2 t0 = ((const ushort2*)(xb + (size_t)s0 * N_FEAT))[lane];
        ushort2 t1 = ((const ushort2*)(xb + (size_t)s1 * N_FEAT))[lane];
        ushort2 t2 = ((const ushort2*)(xb + (size_t)s2 * N_FEAT))[lane];
        ushort2 t3 = ((const ushort2*)(xb + (size_t)s3 * N_FEAT))[lane];
        a0 += bf16_bits_to_f32(t0.x); b0 += bf16_bits_to_f32(t0.y);
        a1 += bf16_bits_to_f32(t1.x); b1 += bf16_bits_to_f32(t1.y);
        a0 += bf16_bits_to_f32(t2.x); b0 += bf16_bits_to_f32(t2.y);
        a1 += bf16_bits_to_f32(t3.x); b1 += bf16_bits_to_f32(t3.y);
    }
    for (; e < end; ++e) {
        int s0 = csr[e];
        ushort2 t0 = ((const ushort2*)(xb + (size_t)s0 * N_FEAT))[lane];
        a0 += bf16_bits_to_f32(t0.x); b0 += bf16_bits_to_f32(t0.y);
    }
    int deg = end - beg;
    float inv = (deg > 0) ? 1.0f / (float)deg : 0.0f;
    ushort2 r;
    r.x = __bfloat16_as_ushort(__float2bfloat16((a0 + a1) * inv));
    r.y = __bfloat16_as_ushort(__float2bfloat16((b0 + b1) * inv));
    ((ushort2*)(out + (size_t)v * N_FEAT))[lane] = r;
}

// h[128 nodes x 128] = relu([x|neigh] @ Wt^T + b), bf16 MFMA, fp32 accum.
__global__ __launch_bounds__(256) void gemm1_mfma_kernel(
    const ushort* __restrict__ xb, const ushort* __restrict__ nbb,
    const ushort* __restrict__ wt, const float* __restrict__ b,
    ushort* __restrict__ h, int n) {
    __shared__ ushort As[128 * 72];
    __shared__ ushort Bs[128 * 72];
    int tid = threadIdx.x;
    int wave = tid >> 6;
    int lane = tid & 63;
    int m = lane & 31;
    int half = lane >> 5;
    int block_row = blockIdx.x * 128;

    f32x16 acc[4];
    #pragma unroll
    for (int t = 0; t < 4; ++t)
        #pragma unroll
        for (int i = 0; i < 16; ++i) acc[t][i] = 0.0f;

    for (int kc = 0; kc < 4; ++kc) {
        const ushort* A = (kc < 2) ? xb : nbb;
        int k0 = (kc & 1) * 64;
        #pragma unroll
        for (int l = 0; l < 4; ++l) {
            int idx = l * 256 + tid;
            int r = idx >> 3;
            int p = idx & 7;
            int node = block_row + r;
            ushort8_t v;
            if (node < n) {
                v = *(const ushort8_t*)(A + (size_t)node * N_FEAT + k0 + p * 8);
            } else {
                #pragma unroll
                for (int q = 0; q < 8; ++q) v[q] = 0;
            }
            *(ushort8_t*)(&As[r * 72 + p * 8]) = v;
        }
        #pragma unroll
        for (int l = 0; l < 4; ++l) {
            int idx = l * 256 + tid;
            int c = idx >> 3;
            int p = idx & 7;
            ushort8_t v = *(const ushort8_t*)(wt + (size_t)c * 256 + kc * 64 + p * 8);
            *(ushort8_t*)(&Bs[c * 72 + p * 8]) = v;
        }
        __syncthreads();
        #pragma unroll
        for (int ks = 0; ks < 4; ++ks) {
            int koff = ks * 16 + half * 8;
            short8 a = *(const short8*)(&As[(32 * wave + m) * 72 + koff]);
            short8 bf0 = *(const short8*)(&Bs[(0 * 32 + m) * 72 + koff]);
            short8 bf1 = *(const short8*)(&Bs[(1 * 32 + m) * 72 + koff]);
            short8 bf2 = *(const short8*)(&Bs[(2 * 32 + m) * 72 + koff]);
            short8 bf3 = *(const short8*)(&Bs[(3 * 32 + m) * 72 + koff]);
            acc[0] = __builtin_amdgcn_mfma_f32_32x32x16_bf16(a, bf0, acc[0], 0, 0, 0);
            acc[1] = __builtin_amdgcn_mfma_f32_32x32x16_bf16(a, bf1, acc[1], 0, 0, 0);
            acc[2] = __builtin_amdgcn_mfma_f32_32x32x16_bf16(a, bf2, acc[2], 0, 0, 0);
            acc[3] = __builtin_amdgcn_mfma_f32_32x32x16_bf16(a, bf3, acc[3], 0, 0, 0);
        }
        __syncthreads();
    }
    #pragma unroll
    for (int t = 0; t < 4; ++t) {
        int col = t * 32 + m;
        float bias = b[col];
        #pragma unroll
        for (int reg = 0; reg < 16; ++reg) {
            int rowin = (reg & 3) + 8 * (reg >> 2) + 4 * half;
            int node = block_row + 32 * wave + rowin;
            if (node < n) {
                float v = fmaxf(acc[t][reg] + bias, 0.0f);
                h[(size_t)node * N_FEAT + col] = __bfloat16_as_ushort(__float2bfloat16(v));
            }
        }
    }
}

// Layer-2 part A: s[v] = h[v]@Ws2, z[v] = h[v]@Wn2 (h bf16). Wave per node.
__global__ void layer2a_kernel(const ushort* __restrict__ h,
                               const float* __restrict__ ws, const float* __restrict__ wn,
                               float* __restrict__ s_out, float* __restrict__ z_out, int n) {
    int v = blockIdx.x * 4 + (threadIdx.x >> 6);
    int lane = threadIdx.x & 63;
    if (v >= n) return;
    ushort2 hb = ((const ushort2*)(h + (size_t)v * N_FEAT))[lane];
    float hx = bf16_bits_to_f32(hb.x);
    float hy = bf16_bits_to_f32(hb.y);
    float4 w0 = ((const float4*)ws)[lane];
    float4 w1 = ((const float4*)wn)[lane];
    float p0 = hx * w0.x + hy * w0.z;
    float p1 = hx * w0.y + hy * w0.w;
    float q0 = hx * w1.x + hy * w1.z;
    float q1 = hx * w1.y + hy * w1.w;
    #pragma unroll
    for (int off = 32; off > 0; off >>= 1) {
        p0 += __shfl_xor(p0, off);
        p1 += __shfl_xor(p1, off);
        q0 += __shfl_xor(q0, off);
        q1 += __shfl_xor(q1, off);
    }
    if (lane == 0) {
        ((float2*)s_out)[v] = make_float2(p0, p1);
        ((float2*)z_out)[v] = make_float2(q0, q1);
    }
}

// Layer-2 part B: aggregate z (L2-resident), add self + bias, log_softmax.
__global__ void layer2b_kernel(const float* __restrict__ s_in, const float* __restrict__ z,
                               const int* __restrict__ row_ptr, const int* __restrict__ csr,
                               const float* __restrict__ b, float* __restrict__ out, int n) {
    int v = blockIdx.x * 256 + threadIdx.x;
    if (v >= n) return;
    int beg = row_ptr[v];
    int end = row_ptr[v + 1];
    float a0 = 0.f, a1 = 0.f, c0 = 0.f, c1 = 0.f;
    int e = beg;
    for (; e + 2 <= end; e += 2) {
        float2 t0 = ((const float2*)z)[csr[e]];
        float2 t1 = ((const float2*)z)[csr[e + 1]];
        a0 += t0.x; a1 += t0.y;
        c0 += t1.x; c1 += t1.y;
    }
    if (e < end) {
        float2 t0 = ((const float2*)z)[csr[e]];
        a0 += t0.x; a1 += t0.y;
    }
    int deg = end - beg;
    float inv = (deg > 0) ? 1.0f / (float)deg : 0.0f;
    float2 sv = ((const float2*)s_in)[v];
    float o0 = sv.x + (a0 + c0) * inv + b[0];
    float o1 = sv.y + (a1 + c1) * inv + b[1];
    float mx = fmaxf(o0, o1);
    float lse = mx + logf(expf(o0 - mx) + expf(o1 - mx));
    ((float2*)out)[v] = make_float2(o0 - lse, o1 - lse);
}

extern "C" void kernel_launch(void* const* d_in, const int* in_sizes, int n_in,
                              void* d_out, int out_size, void* d_ws, size_t ws_size,
                              hipStream_t stream) {
    const float* x        = (const float*)d_in[0];
    const int*   src      = (const int*)d_in[1];
    const int*   dst      = (const int*)d_in[2];
    const float* w_self1  = (const float*)d_in[3];
    const float* w_neigh1 = (const float*)d_in[4];
    const float* b1       = (const float*)d_in[5];
    const float* w_self2  = (const float*)d_in[6];
    const float* w_neigh2 = (const float*)d_in[7];
    const float* b2       = (const float*)d_in[8];
    float* out = (float*)d_out;

    int N = in_sizes[0] / N_FEAT;
    int E = in_sizes[1];
    int nbk = (N + BKT_NODES - 1) / BKT_NODES;  // 782 for N=100000

    char* ws = (char*)d_ws;
    size_t off = 0;
    auto alloc = [&](size_t bytes) -> void* {
        void* p = ws + off;
        off += (bytes + 255) & ~(size_t)255;
        return p;
    };
    int*      cnt2         = (int*)alloc((size_t)nbk * STRIPES * 4);
    int*      bucket_start = (int*)alloc((size_t)nbk * 4);
    int*      row_ptr      = (int*)alloc((size_t)(N + 1) * 4);
    int*      csr          = (int*)alloc((size_t)E * 4);
    unsigned* buf          = (unsigned*)alloc((size_t)nbk * BCAP * 4);
    ushort*   xb           = (ushort*)alloc((size_t)N * N_FEAT * 2);
    ushort*   nbb          = (ushort*)alloc((size_t)N * N_FEAT * 2);
    ushort*   h            = (ushort*)alloc((size_t)N * N_FEAT * 2);
    ushort*   wt           = (ushort*)alloc((size_t)128 * 256 * 2);
    float*    s_buf        = (float*)alloc((size_t)N * 2 * 4);
    float*    z_buf        = (float*)alloc((size_t)N * 2 * 4);
    (void)ws_size; (void)n_in; (void)out_size;
    // ~99 MB total

    hipMemsetAsync(cnt2, 0, (size_t)nbk * STRIPES * 4, stream);

    bucket_scatter_kernel<<<(E + 255) / 256, 256, 0, stream>>>(src, dst, cnt2, buf, E);
    bucket_scan_kernel<<<1, 1024, 0, stream>>>(cnt2, bucket_start, row_ptr, nbk, N, E);
    build_csr_kernel<<<nbk, 256, 0, stream>>>(buf, cnt2, bucket_start, row_ptr, csr, N);

    to_bf16_kernel<<<1024, 256, 0, stream>>>(x, xb, N * N_FEAT / 4);
    prep_weights_kernel<<<(128 * 256 + 255) / 256, 256, 0, stream>>>(w_self1, w_neigh1, wt);
    aggregate_bf16_kernel<<<(N + 3) / 4, 256, 0, stream>>>(xb, row_ptr, csr, nbb, N);
    gemm1_mfma_kernel<<<(N + 127) / 128, 256, 0, stream>>>(xb, nbb, wt, b1, h, N);
    layer2a_kernel<<<(N + 3) / 4, 256, 0, stream>>>(h, w_self2, w_neigh2, s_buf, z_buf, N);
    layer2b_kernel<<<(N + 255) / 256, 256, 0, stream>>>(s_buf, z_buf, row_ptr, csr, b2, out, N);
}

// Round 5
// 284.993 us; speedup vs baseline: 2.2613x; 1.1855x over previous
//
#include <hip/hip_runtime.h>
#include <hip/hip_bf16.h>

// SAGE 2-layer forward, R5:
//   neigh1 = segment_mean(x[src]); h = relu(x@Ws1 + neigh1@Wn1 + b1)   [bf16 MFMA]
//   z = h@Wn2, s = h@Ws2; out = log_softmax(s + segment_mean(z) + b2)
// R5 changes vs R4:
//   - CSR build -> LDS-staged 2-level radix:
//     Pass A: multisplit into 98 coarse buckets (1024 nodes), LDS staging, bucket-
//       contiguous flushes (avg 168B chunks) -> WRITE 59MB -> ~7MB
//     Pass B: per coarse bucket counting sort into its contiguous CSR window
//       (65KB, L2-resident -> full-line writes), emits row_ptr coalesced.

#define N_FEAT 128
#define CSHIFT 10                 // 1024 nodes per coarse bucket
#define CNODES 1024
#define CCAP 18432                // mean 16327, sd 127 -> +16 sigma
#define BATCH 4096                // edges per pass-A block

typedef __attribute__((ext_vector_type(8))) short short8;
typedef __attribute__((ext_vector_type(8))) unsigned short ushort8_t;
typedef __attribute__((ext_vector_type(16))) float f32x16;

// Pass A: LDS-staged multisplit into coarse buckets. pack = (d&1023)<<17 | src.
__global__ __launch_bounds__(256) void multisplit_kernel(
    const int* __restrict__ src, const int* __restrict__ dst,
    int* __restrict__ ccursor, unsigned* __restrict__ cbuf, int E) {
    __shared__ unsigned stage[BATCH];
    __shared__ int cnt[128];
    __shared__ int s[128];
    __shared__ int excl[128];
    __shared__ int incl[128];
    __shared__ int cur[128];
    __shared__ int gpos[128];
    int tid = threadIdx.x;
    int base = blockIdx.x * BATCH;
    int total = min(BATCH, E - base);

    unsigned pk[16];
    int bn[16];
    if (tid < 128) cnt[tid] = 0;
    __syncthreads();
    #pragma unroll
    for (int k = 0; k < 16; ++k) {
        int e = base + k * 256 + tid;
        if (e < E) {
            int d = dst[e];
            int sv = src[e];
            bn[k] = d >> CSHIFT;
            pk[k] = ((unsigned)(d & (CNODES - 1)) << 17) | (unsigned)sv;
            atomicAdd(&cnt[bn[k]], 1);
        } else {
            bn[k] = -1;
        }
    }
    __syncthreads();
    // exclusive scan of 128 bins
    int c = (tid < 128) ? cnt[tid] : 0;
    int val = c;
    if (tid < 128) s[tid] = val;
    __syncthreads();
    for (int off = 1; off < 128; off <<= 1) {
        int t = (tid >= off && tid < 128) ? s[tid - off] : 0;
        __syncthreads();
        if (tid < 128) { val += t; s[tid] = val; }
        __syncthreads();
    }
    if (tid < 128) {
        incl[tid] = val;
        excl[tid] = val - c;
        cur[tid] = val - c;
        gpos[tid] = (c > 0) ? atomicAdd(&ccursor[tid], c) : 0;
    }
    __syncthreads();
    // shuffle into staging (bucket-sorted within block)
    #pragma unroll
    for (int k = 0; k < 16; ++k) {
        if (bn[k] >= 0) {
            int ofs = atomicAdd(&cur[bn[k]], 1);
            stage[ofs] = pk[k];
        }
    }
    __syncthreads();
    // flush: consecutive i within a bucket -> consecutive global targets
    for (int i = tid; i < total; i += 256) {
        int lo = 0, hi = 127;
        while (lo < hi) {
            int mid = (lo + hi) >> 1;
            if (incl[mid] > i) hi = mid; else lo = mid + 1;
        }
        int b = lo;
        int target = gpos[b] + (i - excl[b]);
        cbuf[(size_t)b * CCAP + target] = stage[i];
    }
}

// Tiny scan of coarse counts -> CSR start per coarse bucket; seeds row_ptr[N]=E.
__global__ void coarse_scan_kernel(const int* __restrict__ ccnt, int* __restrict__ cstart,
                                   int* __restrict__ row_ptr, int nbk, int N, int E) {
    __shared__ int s[128];
    int tid = threadIdx.x;
    int c = (tid < nbk) ? ccnt[tid] : 0;
    int val = c;
    s[tid] = val;
    __syncthreads();
    for (int off = 1; off < 128; off <<= 1) {
        int t = (tid >= off) ? s[tid - off] : 0;
        __syncthreads();
        val += t;
        s[tid] = val;
        __syncthreads();
    }
    if (tid < nbk) cstart[tid] = val - c;
    if (tid == 0) row_ptr[N] = E;
}

// Pass B: one block (1024 thr) per coarse bucket: counting sort into the bucket's
// contiguous CSR window; row_ptr written coalesced.
__global__ __launch_bounds__(1024) void build_csr2_kernel(
    const unsigned* __restrict__ cbuf, const int* __restrict__ ccnt,
    const int* __restrict__ cstart, int* __restrict__ row_ptr,
    int* __restrict__ csr, int N) {
    __shared__ int hist[CNODES];
    __shared__ int s[CNODES];
    __shared__ int cur[CNODES];
    int cb = blockIdx.x;
    int tid = threadIdx.x;
    int cnt = ccnt[cb];
    int base = cstart[cb];
    size_t bbase = (size_t)cb * CCAP;
    hist[tid] = 0;
    __syncthreads();
    for (int e = tid; e < cnt; e += 1024) {
        unsigned p = cbuf[bbase + e];
        atomicAdd(&hist[p >> 17], 1);
    }
    __syncthreads();
    int c = hist[tid];
    int val = c;
    s[tid] = val;
    __syncthreads();
    for (int off = 1; off < 1024; off <<= 1) {
        int t = (tid >= off) ? s[tid - off] : 0;
        __syncthreads();
        val += t;
        s[tid] = val;
        __syncthreads();
    }
    int excl = val - c;
    int node = cb * CNODES + tid;
    if (node < N) row_ptr[node] = base + excl;
    cur[tid] = excl;
    __syncthreads();
    for (int e = tid; e < cnt; e += 1024) {
        unsigned p = cbuf[bbase + e];
        int bin = p >> 17;
        int ofs = atomicAdd(&cur[bin], 1);
        csr[base + ofs] = (int)(p & 0x1FFFF);
    }
}

__global__ void to_bf16_kernel(const float* __restrict__ x, ushort* __restrict__ xb, int n4) {
    int i = blockIdx.x * 256 + threadIdx.x;
    int stride = gridDim.x * 256;
    for (; i < n4; i += stride) {
        float4 v = ((const float4*)x)[i];
        ushort4 r;
        r.x = __bfloat16_as_ushort(__float2bfloat16(v.x));
        r.y = __bfloat16_as_ushort(__float2bfloat16(v.y));
        r.z = __bfloat16_as_ushort(__float2bfloat16(v.z));
        r.w = __bfloat16_as_ushort(__float2bfloat16(v.w));
        ((ushort4*)xb)[i] = r;
    }
}

// Build Wt[n=128][k=256] bf16 from w_self1 (k 0..127) / w_neigh1 (k 128..255), both [k][n] fp32.
__global__ void prep_weights_kernel(const float* __restrict__ w1, const float* __restrict__ w2,
                                    ushort* __restrict__ wt) {
    int id = blockIdx.x * 256 + threadIdx.x;
    if (id >= 128 * 256) return;
    int nn = id >> 8;
    int k = id & 255;
    float v = (k < 128) ? w1[k * 128 + nn] : w2[(k - 128) * 128 + nn];
    wt[nn * 256 + k] = __bfloat16_as_ushort(__float2bfloat16(v));
}

__device__ __forceinline__ float bf16_bits_to_f32(ushort u) {
    union { unsigned int i; float f; } c;
    c.i = ((unsigned int)u) << 16;
    return c.f;
}

// One wave per node; bf16 gather, fp32 accum, bf16 output.
__global__ void aggregate_bf16_kernel(const ushort* __restrict__ xb,
                                      const int* __restrict__ row_ptr,
                                      const int* __restrict__ csr,
                                      ushort* __restrict__ out, int n) {
    int v = blockIdx.x * 4 + (threadIdx.x >> 6);
    int lane = threadIdx.x & 63;
    if (v >= n) return;
    int beg = row_ptr[v];
    int end = row_ptr[v + 1];
    float a0 = 0.f, b0 = 0.f, a1 = 0.f, b1 = 0.f;
    int e = beg;
    for (; e + 4 <= end; e += 4) {
        int s0 = csr[e], s1 = csr[e + 1], s2 = csr[e + 2], s3 = csr[e + 3];
        ushort2 t0 = ((const ushort2*)(xb + (size_t)s0 * N_FEAT))[lane];
        ushort2 t1 = ((const ushort2*)(xb + (size_t)s1 * N_FEAT))[lane];
        ushort2 t2 = ((const ushort2*)(xb + (size_t)s2 * N_FEAT))[lane];
        ushort2 t3 = ((const ushort2*)(xb + (size_t)s3 * N_FEAT))[lane];
        a0 += bf16_bits_to_f32(t0.x); b0 += bf16_bits_to_f32(t0.y);
        a1 += bf16_bits_to_f32(t1.x); b1 += bf16_bits_to_f32(t1.y);
        a0 += bf16_bits_to_f32(t2.x); b0 += bf16_bits_to_f32(t2.y);
        a1 += bf16_bits_to_f32(t3.x); b1 += bf16_bits_to_f32(t3.y);
    }
    for (; e < end; ++e) {
        int s0 = csr[e];
        ushort2 t0 = ((const ushort2*)(xb + (size_t)s0 * N_FEAT))[lane];
        a0 += bf16_bits_to_f32(t0.x); b0 += bf16_bits_to_f32(t0.y);
    }
    int deg = end - beg;
    float inv = (deg > 0) ? 1.0f / (float)deg : 0.0f;
    ushort2 r;
    r.x = __bfloat16_as_ushort(__float2bfloat16((a0 + a1) * inv));
    r.y = __bfloat16_as_ushort(__float2bfloat16((b0 + b1) * inv));
    ((ushort2*)(out + (size_t)v * N_FEAT))[lane] = r;
}

// h[128 nodes x 128] = relu([x|neigh] @ Wt^T + b), bf16 MFMA, fp32 accum.
__global__ __launch_bounds__(256) void gemm1_mfma_kernel(
    const ushort* __restrict__ xb, const ushort* __restrict__ nbb,
    const ushort* __restrict__ wt, const float* __restrict__ b,
    ushort* __restrict__ h, int n) {
    __shared__ ushort As[128 * 72];
    __shared__ ushort Bs[128 * 72];
    int tid = threadIdx.x;
    int wave = tid >> 6;
    int lane = tid & 63;
    int m = lane & 31;
    int half = lane >> 5;
    int block_row = blockIdx.x * 128;

    f32x16 acc[4];
    #pragma unroll
    for (int t = 0; t < 4; ++t)
        #pragma unroll
        for (int i = 0; i < 16; ++i) acc[t][i] = 0.0f;

    for (int kc = 0; kc < 4; ++kc) {
        const ushort* A = (kc < 2) ? xb : nbb;
        int k0 = (kc & 1) * 64;
        #pragma unroll
        for (int l = 0; l < 4; ++l) {
            int idx = l * 256 + tid;
            int r = idx >> 3;
            int p = idx & 7;
            int node = block_row + r;
            ushort8_t v;
            if (node < n) {
                v = *(const ushort8_t*)(A + (size_t)node * N_FEAT + k0 + p * 8);
            } else {
                #pragma unroll
                for (int q = 0; q < 8; ++q) v[q] = 0;
            }
            *(ushort8_t*)(&As[r * 72 + p * 8]) = v;
        }
        #pragma unroll
        for (int l = 0; l < 4; ++l) {
            int idx = l * 256 + tid;
            int cc = idx >> 3;
            int p = idx & 7;
            ushort8_t v = *(const ushort8_t*)(wt + (size_t)cc * 256 + kc * 64 + p * 8);
            *(ushort8_t*)(&Bs[cc * 72 + p * 8]) = v;
        }
        __syncthreads();
        #pragma unroll
        for (int ks = 0; ks < 4; ++ks) {
            int koff = ks * 16 + half * 8;
            short8 a = *(const short8*)(&As[(32 * wave + m) * 72 + koff]);
            short8 bf0 = *(const short8*)(&Bs[(0 * 32 + m) * 72 + koff]);
            short8 bf1 = *(const short8*)(&Bs[(1 * 32 + m) * 72 + koff]);
            short8 bf2 = *(const short8*)(&Bs[(2 * 32 + m) * 72 + koff]);
            short8 bf3 = *(const short8*)(&Bs[(3 * 32 + m) * 72 + koff]);
            acc[0] = __builtin_amdgcn_mfma_f32_32x32x16_bf16(a, bf0, acc[0], 0, 0, 0);
            acc[1] = __builtin_amdgcn_mfma_f32_32x32x16_bf16(a, bf1, acc[1], 0, 0, 0);
            acc[2] = __builtin_amdgcn_mfma_f32_32x32x16_bf16(a, bf2, acc[2], 0, 0, 0);
            acc[3] = __builtin_amdgcn_mfma_f32_32x32x16_bf16(a, bf3, acc[3], 0, 0, 0);
        }
        __syncthreads();
    }
    #pragma unroll
    for (int t = 0; t < 4; ++t) {
        int col = t * 32 + m;
        float bias = b[col];
        #pragma unroll
        for (int reg = 0; reg < 16; ++reg) {
            int rowin = (reg & 3) + 8 * (reg >> 2) + 4 * half;
            int node = block_row + 32 * wave + rowin;
            if (node < n) {
                float v = fmaxf(acc[t][reg] + bias, 0.0f);
                h[(size_t)node * N_FEAT + col] = __bfloat16_as_ushort(__float2bfloat16(v));
            }
        }
    }
}

// Layer-2 part A: s[v] = h[v]@Ws2, z[v] = h[v]@Wn2 (h bf16). Wave per node.
__global__ void layer2a_kernel(const ushort* __restrict__ h,
                               const float* __restrict__ ws, const float* __restrict__ wn,
                               float* __restrict__ s_out, float* __restrict__ z_out, int n) {
    int v = blockIdx.x * 4 + (threadIdx.x >> 6);
    int lane = threadIdx.x & 63;
    if (v >= n) return;
    ushort2 hb = ((const ushort2*)(h + (size_t)v * N_FEAT))[lane];
    float hx = bf16_bits_to_f32(hb.x);
    float hy = bf16_bits_to_f32(hb.y);
    float4 w0 = ((const float4*)ws)[lane];
    float4 w1 = ((const float4*)wn)[lane];
    float p0 = hx * w0.x + hy * w0.z;
    float p1 = hx * w0.y + hy * w0.w;
    float q0 = hx * w1.x + hy * w1.z;
    float q1 = hx * w1.y + hy * w1.w;
    #pragma unroll
    for (int off = 32; off > 0; off >>= 1) {
        p0 += __shfl_xor(p0, off);
        p1 += __shfl_xor(p1, off);
        q0 += __shfl_xor(q0, off);
        q1 += __shfl_xor(q1, off);
    }
    if (lane == 0) {
        ((float2*)s_out)[v] = make_float2(p0, p1);
        ((float2*)z_out)[v] = make_float2(q0, q1);
    }
}

// Layer-2 part B: aggregate z (L2-resident), add self + bias, log_softmax.
__global__ void layer2b_kernel(const float* __restrict__ s_in, const float* __restrict__ z,
                               const int* __restrict__ row_ptr, const int* __restrict__ csr,
                               const float* __restrict__ b, float* __restrict__ out, int n) {
    int v = blockIdx.x * 256 + threadIdx.x;
    if (v >= n) return;
    int beg = row_ptr[v];
    int end = row_ptr[v + 1];
    float a0 = 0.f, a1 = 0.f, c0 = 0.f, c1 = 0.f;
    int e = beg;
    for (; e + 2 <= end; e += 2) {
        float2 t0 = ((const float2*)z)[csr[e]];
        float2 t1 = ((const float2*)z)[csr[e + 1]];
        a0 += t0.x; a1 += t0.y;
        c0 += t1.x; c1 += t1.y;
    }
    if (e < end) {
        float2 t0 = ((const float2*)z)[csr[e]];
        a0 += t0.x; a1 += t0.y;
    }
    int deg = end - beg;
    float inv = (deg > 0) ? 1.0f / (float)deg : 0.0f;
    float2 sv = ((const float2*)s_in)[v];
    float o0 = sv.x + (a0 + c0) * inv + b[0];
    float o1 = sv.y + (a1 + c1) * inv + b[1];
    float mx = fmaxf(o0, o1);
    float lse = mx + logf(expf(o0 - mx) + expf(o1 - mx));
    ((float2*)out)[v] = make_float2(o0 - lse, o1 - lse);
}

extern "C" void kernel_launch(void* const* d_in, const int* in_sizes, int n_in,
                              void* d_out, int out_size, void* d_ws, size_t ws_size,
                              hipStream_t stream) {
    const float* x        = (const float*)d_in[0];
    const int*   src      = (const int*)d_in[1];
    const int*   dst      = (const int*)d_in[2];
    const float* w_self1  = (const float*)d_in[3];
    const float* w_neigh1 = (const float*)d_in[4];
    const float* b1       = (const float*)d_in[5];
    const float* w_self2  = (const float*)d_in[6];
    const float* w_neigh2 = (const float*)d_in[7];
    const float* b2       = (const float*)d_in[8];
    float* out = (float*)d_out;

    int N = in_sizes[0] / N_FEAT;
    int E = in_sizes[1];
    int nbk = (N + CNODES - 1) / CNODES;  // 98 for N=100000

    char* ws = (char*)d_ws;
    size_t off = 0;
    auto alloc = [&](size_t bytes) -> void* {
        void* p = ws + off;
        off += (bytes + 255) & ~(size_t)255;
        return p;
    };
    int*      ccursor = (int*)alloc(128 * 4);
    int*      cstart  = (int*)alloc(128 * 4);
    int*      row_ptr = (int*)alloc((size_t)(N + 1) * 4);
    int*      csr     = (int*)alloc((size_t)E * 4);
    unsigned* cbuf    = (unsigned*)alloc((size_t)nbk * CCAP * 4);
    ushort*   xb      = (ushort*)alloc((size_t)N * N_FEAT * 2);
    ushort*   nbb     = (ushort*)alloc((size_t)N * N_FEAT * 2);
    ushort*   h       = (ushort*)alloc((size_t)N * N_FEAT * 2);
    ushort*   wt      = (ushort*)alloc((size_t)128 * 256 * 2);
    float*    s_buf   = (float*)alloc((size_t)N * 2 * 4);
    float*    z_buf   = (float*)alloc((size_t)N * 2 * 4);
    (void)ws_size; (void)n_in; (void)out_size;

    hipMemsetAsync(ccursor, 0, 128 * 4, stream);

    multisplit_kernel<<<(E + BATCH - 1) / BATCH, 256, 0, stream>>>(src, dst, ccursor, cbuf, E);
    coarse_scan_kernel<<<1, 128, 0, stream>>>(ccursor, cstart, row_ptr, nbk, N, E);
    build_csr2_kernel<<<nbk, 1024, 0, stream>>>(cbuf, ccursor, cstart, row_ptr, csr, N);

    to_bf16_kernel<<<1024, 256, 0, stream>>>(x, xb, N * N_FEAT / 4);
    prep_weights_kernel<<<(128 * 256 + 255) / 256, 256, 0, stream>>>(w_self1, w_neigh1, wt);
    aggregate_bf16_kernel<<<(N + 3) / 4, 256, 0, stream>>>(xb, row_ptr, csr, nbb, N);
    gemm1_mfma_kernel<<<(N + 127) / 128, 256, 0, stream>>>(xb, nbb, wt, b1, h, N);
    layer2a_kernel<<<(N + 3) / 4, 256, 0, stream>>>(h, w_self2, w_neigh2, s_buf, z_buf, N);
    layer2b_kernel<<<(N + 255) / 256, 256, 0, stream>>>(s_buf, z_buf, row_ptr, csr, b2, out, N);
}